// Round 13
// baseline (407.808 us; speedup 1.0000x reference)
//
#include <hip/hip_runtime.h>
#include <hip/hip_bf16.h>

typedef __hip_bfloat16 bf16;

#define GNUM 256
#define LN_EPS 1e-5f
#define MSG_EPS 1e-7f

typedef float f4v __attribute__((ext_vector_type(4)));
typedef short s8v __attribute__((ext_vector_type(8)));
typedef __bf16 b8v __attribute__((ext_vector_type(8)));

template <typename V>
__device__ auto mfma_bf16_(V a, V b, f4v c, int)
    -> decltype(__builtin_amdgcn_mfma_f32_16x16x32_bf16(a, b, c, 0, 0, 0)) {
  return __builtin_amdgcn_mfma_f32_16x16x32_bf16(a, b, c, 0, 0, 0);
}
template <typename V>
__device__ f4v mfma_bf16_(V a, V b, f4v c, long) {
  return __builtin_amdgcn_mfma_f32_16x16x32_bf16(__builtin_bit_cast(s8v, a),
                                                 __builtin_bit_cast(s8v, b), c, 0, 0, 0);
}
__device__ __forceinline__ f4v mfma16(uint4 a, uint4 b, f4v c){
  return mfma_bf16_(__builtin_bit_cast(b8v, a), __builtin_bit_cast(b8v, b), c, 0);
}

__device__ __forceinline__ float bu2f(unsigned short u){
  unsigned v = ((unsigned)u) << 16; return __builtin_bit_cast(float, v);
}
__device__ __forceinline__ unsigned short f2bu(float f){
  unsigned u = __builtin_bit_cast(unsigned, f);
  return (unsigned short)((u + 0x7FFFu + ((u >> 16) & 1u)) >> 16);
}

__device__ __forceinline__ float wave_sum64(float v){
  #pragma unroll
  for (int off = 32; off > 0; off >>= 1) v += __shfl_xor(v, off, 64);
  return v;
}

struct Params15 {
  const void* src[15];
  int n[15];
  int off[15];
};

// JOURNAL:
//  R5: no cooperative grid.sync -- ~100us/sync on 8 XCDs.
//  R7: no serial wave_sum64 recompute in low-occupancy k_vn (+58us).
//  R8: mode-0 k_layer write-bytes NOT on critical path (gather-bound).
//  R9: always-16 agg batch regressed (+38% gather issues); vt-fold WORKED.
//  R10: deg-specialized batch (8/16 by deg) + vt-fold = 337us best.
//  R11: k_prep merged into k_front = 332us.
//  R12: CSR chain 5->3 dispatches: neutral -- prologue launches ~free in
//       graph; prologue lever class exhausted.
//  R13: 4-row-interleaved first batch in k_layer agg: rows are independent,
//       so issue all 4 rows' payload loads + gathers before any compute
//       (per-wave serial chains 5.6 -> ~2.6). Remainders (deg>8) stay
//       per-row 8-deep serial. +64 VGPR accepted (occ was 53% anyway).

// k_front block roles (each derives isf locally; roles read RAW inputs):
//   0..127          : param convert -> par, zero vt, block0 publishes flag
//   128..191        : permute gcn_W (raw src[2]) into MFMA B-frag order Wf
//   192..193        : goffs binary search over batch
//   194..194+eGrid  : degree count atomics (counts pre-zeroed by memset)
//   rest            : node encode b0[i,:] = bf16(sum_f atom_emb + vn_emb)
__global__ __launch_bounds__(256) void k_front(
    Params15 P, int* __restrict__ flag, float* __restrict__ par,
    int* __restrict__ counts, float* __restrict__ vt, int nvt,
    const int* __restrict__ x, const int* __restrict__ batch,
    const int* __restrict__ dstp,
    unsigned short* __restrict__ Wf, int* __restrict__ goffs,
    unsigned short* __restrict__ b0, int n, int E, int eGrid){
  __shared__ int isf_sh;
  int tid = threadIdx.x, bid = blockIdx.x;
  if (tid < 64){
    const unsigned short* u = (const unsigned short*)P.src[0];
    int bad = 0;
    for (int k = tid; k < 256; k += 64){
      unsigned short v = u[2*k];
      if (((v >> 7) & 0xFFu) >= 137u) bad = 1;
    }
    unsigned long long m = __ballot(bad);
    if (tid == 0) isf_sh = (m != 0ull) ? 1 : 0;
  }
  __syncthreads();
  bool isf = (isf_sh != 0);

  if (bid < 128){
    if (bid == 0 && tid == 0) *flag = isf ? 1 : 0;
    int stride = 128*256;
    int gid = bid*256 + tid;
    for (int a = 0; a < 15; ++a){
      int nn = P.n[a];
      float* d = par + P.off[a];
      if (isf){
        const float* s = (const float*)P.src[a];
        for (int i = gid; i < nn; i += stride) d[i] = s[i];
      } else {
        const bf16* s = (const bf16*)P.src[a];
        for (int i = gid; i < nn; i += stride) d[i] = __bfloat162float(s[i]);
      }
    }
    for (int i = gid; i < nvt; i += stride) vt[i] = 0.f;
  } else if (bid < 192){
    int t = (bid - 128)*256 + tid;      // 16384 total
    int j = t & 7, lane = (t >> 3) & 63, nt = (t >> 9) & 3, kt = (t >> 11) & 1, l = t >> 12;
    int k = kt*32 + (lane >> 4)*8 + j;
    int c = nt*16 + (lane & 15);
    int src = l*4096 + k*64 + c;
    if (isf) Wf[t] = f2bu(((const float*)P.src[2])[src]);
    else     Wf[t] = ((const unsigned short*)P.src[2])[src];
  } else if (bid < 194){
    int g = (bid - 192)*256 + tid;
    if (g > GNUM) return;
    if (g == GNUM){ goffs[GNUM] = n; return; }
    int lo = 0, hi = n;
    while (lo < hi){ int mid = (lo+hi)>>1; if (batch[mid] < g) lo = mid+1; else hi = mid; }
    goffs[g] = lo;
  } else if (bid < 194 + eGrid){
    int e = (bid - 194)*256 + tid;
    if (e < E) atomicAdd(counts + dstp[e], 1);
  } else {
    int t = (bid - 194 - eGrid) * 256 + tid;
    int i = t >> 6, j = t & 63;
    if (i >= n) return;
    float acc;
    if (isf){
      const float* ae = (const float*)P.src[0];
      acc = ((const float*)P.src[6])[j];
      #pragma unroll
      for (int f = 0; f < 9; ++f){
        int idx = x[i*9 + f];
        acc += ae[(f*64 + idx)*64 + j];
      }
    } else {
      const unsigned short* ae = (const unsigned short*)P.src[0];
      acc = bu2f(((const unsigned short*)P.src[6])[j]);
      #pragma unroll
      for (int f = 0; f < 9; ++f){
        int idx = x[i*9 + f];
        acc += bu2f(ae[(f*64 + idx)*64 + j]);
      }
    }
    b0[t] = f2bu(acc);
  }
}

// scan1: per-chunk inclusive scan -> offs[i+1] (partial), plus
// cursor[i] = partial EXCLUSIVE prefix (lets scatter add bexc on the fly).
__global__ __launch_bounds__(256) void k_scan1(const int* __restrict__ counts,
                                               int* __restrict__ offs,
                                               int* __restrict__ cursor,
                                               int* __restrict__ btot, int n){
  __shared__ int wsum[4];
  int tid = threadIdx.x, w = tid >> 6, lane = tid & 63;
  int i = blockIdx.x*256 + tid;
  int v = (i < n) ? counts[i] : 0;
  int incl = v;
  #pragma unroll
  for (int off = 1; off < 64; off <<= 1){
    int t = __shfl_up(incl, off, 64);
    if (lane >= off) incl += t;
  }
  if (lane == 63) wsum[w] = incl;
  __syncthreads();
  int woff = 0;
  for (int k = 0; k < w; ++k) woff += wsum[k];
  int tot = incl + woff;
  if (i < n){
    offs[i+1] = tot;
    cursor[i] = tot - v;              // partial exclusive
  }
  if (tid == 255) btot[blockIdx.x] = tot;
}

__global__ __launch_bounds__(256) void k_scan2(const int* __restrict__ btot,
                                               int* __restrict__ bexc, int nb){
  __shared__ int wsum[4];
  __shared__ int carry_sh;
  int tid = threadIdx.x, w = tid >> 6, lane = tid & 63;
  if (tid == 0) carry_sh = 0;
  __syncthreads();
  for (int base = 0; base < nb; base += 256){
    int i = base + tid;
    int v = (i < nb) ? btot[i] : 0;
    int incl = v;
    #pragma unroll
    for (int off = 1; off < 64; off <<= 1){
      int t = __shfl_up(incl, off, 64);
      if (lane >= off) incl += t;
    }
    if (lane == 63) wsum[w] = incl;
    __syncthreads();
    int carry = carry_sh;
    int woff = 0;
    for (int k = 0; k < w; ++k) woff += wsum[k];
    if (i < nb) bexc[i] = carry + woff + incl - v;
    __syncthreads();
    if (tid == 0) carry_sh = carry + wsum[0] + wsum[1] + wsum[2] + wsum[3];
    __syncthreads();
  }
}

// k_scatfin = merged scan3 + scatter (role-split, no intra-kernel dependency)
__global__ void k_scatfin(const int* __restrict__ src, const int* __restrict__ dst,
                          const int* __restrict__ ea, int* __restrict__ offs,
                          int* __restrict__ cursor, const int* __restrict__ bexc,
                          int* __restrict__ payload, int n, int E, int nScanB){
  int bid = blockIdx.x, tid = threadIdx.x;
  if (bid < nScanB){
    int i = bid*256 + tid;
    if (i == 0) offs[0] = 0;
    if (i < n) offs[i+1] += bexc[bid];
  } else {
    int e = (bid - nScanB)*256 + tid;
    if (e >= E) return;
    int d = dst[e];
    int pos = atomicAdd(cursor + d, 1) + bexc[d >> 8];
    payload[pos] = (src[e] & 0xFFFF) | (ea[e*3] << 16) | (ea[e*3+1] << 19) | (ea[e*3+2] << 22);
  }
}

// Fused GENConv layer, 256 threads = 4 waves, block owns 16 rows.
// R13 agg: 4-ROW-INTERLEAVED first batch-8 -- all 4 rows' payload loads,
// then all 4 rows' gathers, issue back-to-back (32 loads in flight) before
// any compute; per-row deg>8 remainders stay 8-deep serial (R10 path).
// Loads unguarded clamped; compute uniform-skipped; all r-loops unrolled
// (runtime-indexed arrays would spill to scratch).
// Epilogue (mode 0): hres+rowstat + h2 into H2 LDS (stride 65) -> vt atomics.
// mode 1: finalout = LN(.)
__global__ __launch_bounds__(256) void k_layer(
    const unsigned short* __restrict__ b0, const int* __restrict__ offs,
    const int* __restrict__ payload, const float* __restrict__ bond,
    const unsigned short* __restrict__ Wf, const float* __restrict__ bias,
    const int* __restrict__ batch, float* __restrict__ vt,
    unsigned short* __restrict__ hres, float2* __restrict__ rowstat,
    void* __restrict__ finalout, const float* __restrict__ ng,
    const float* __restrict__ nb, const int* __restrict__ flag,
    int use_res, int mode, int n){
  __shared__ float Bs[1536];          // bond tables during agg; H2 staging in epilogue
  __shared__ __align__(16) unsigned short T[16][72];  // 144B row stride: 2-way alias = free
  __shared__ float PS1[4][16], PS2[4][16];
  __shared__ int batch_lds[16];
  int tid = threadIdx.x;
  int v0 = blockIdx.x * 16;
  for (int idx = tid; idx < 1536; idx += 256) Bs[idx] = bond[idx];
  if (tid < 16){ int rw = v0 + tid; batch_lds[tid] = (rw < n) ? batch[rw] : -1; }
  __syncthreads();
  int w = tid >> 6, j = tid & 63;
  int vb = v0 + w*4;                  // this wave's 4 rows

  // hoist the 5 CSR offsets for this wave: one coalesced lane-parallel load
  int oidx = vb + (j < 5 ? j : 4);
  if (oidx > n) oidx = n;
  int o5 = offs[oidx];

  // ---- interleaved agg: ranges + own-values for all 4 rows first
  int e0a[4], e1a[4];
  float own[4], den[4], num[4];
  #pragma unroll
  for (int r = 0; r < 4; ++r){
    int v = vb + r;
    int e0 = __builtin_amdgcn_readfirstlane(__shfl(o5, r, 64));
    int e1 = __builtin_amdgcn_readfirstlane(__shfl(o5, r + 1, 64));
    if (v >= n || e1 <= e0){ e0 = 0; e1 = 0; }   // deg-0 / OOB: safe clamp
    e0a[r] = e0; e1a[r] = e1;
    own[r] = (v < n) ? bu2f(b0[((unsigned)v << 6) + j]) : 0.f;
    den[r] = 0.f; num[r] = 0.f;
  }

  // first batch-8 for ALL rows: 32 payload s_loads, then 32 gathers in flight
  int pu[4][8]; float hv[4][8];
  #pragma unroll
  for (int r = 0; r < 4; ++r){
    int rem = e1a[r] - e0a[r];
    #pragma unroll
    for (int u = 0; u < 8; ++u){
      int ei = (u < rem) ? e0a[r] + u : e0a[r];
      pu[r][u] = payload[ei];
    }
  }
  #pragma unroll
  for (int r = 0; r < 4; ++r)
    #pragma unroll
    for (int u = 0; u < 8; ++u)
      hv[r][u] = bu2f(b0[((unsigned)(pu[r][u] & 0xFFFF) << 6) + j]);

  // compute first batch (uniform skip per row)
  #pragma unroll
  for (int r = 0; r < 4; ++r){
    int rem = e1a[r] - e0a[r];
    if (rem <= 0) continue;
    if (rem >= 8){
      #pragma unroll
      for (int u = 0; u < 8; ++u){
        int p = pu[r][u];
        float eev = Bs[((p >> 16) & 7)*64 + j]
                  + Bs[(8 + ((p >> 19) & 7))*64 + j]
                  + Bs[(16 + ((p >> 22) & 7))*64 + j];
        float mm = fmaxf(hv[r][u] + eev, 0.f) + MSG_EPS;
        float ex = __expf(mm);
        den[r] += ex;
        num[r] = fmaf(ex, mm, num[r]);
      }
    } else {
      #pragma unroll
      for (int u = 0; u < 8; ++u){
        if (u < rem){
          int p = pu[r][u];
          float eev = Bs[((p >> 16) & 7)*64 + j]
                    + Bs[(8 + ((p >> 19) & 7))*64 + j]
                    + Bs[(16 + ((p >> 22) & 7))*64 + j];
          float mm = fmaxf(hv[r][u] + eev, 0.f) + MSG_EPS;
          float ex = __expf(mm);
          den[r] += ex;
          num[r] = fmaf(ex, mm, num[r]);
        }
      }
    }
  }

  // remainders (deg>8, ~41% of rows): per-row 8-deep batches (R10 path)
  #pragma unroll
  for (int r = 0; r < 4; ++r){
    for (int e = e0a[r] + 8; e < e1a[r]; e += 8){
      int rem = e1a[r] - e;
      int pu8[8]; float hv8[8];
      #pragma unroll
      for (int u = 0; u < 8; ++u){
        int ei = (u < rem) ? e + u : e0a[r];
        pu8[u] = payload[ei];
      }
      #pragma unroll
      for (int u = 0; u < 8; ++u)
        hv8[u] = bu2f(b0[((unsigned)(pu8[u] & 0xFFFF) << 6) + j]);
      #pragma unroll
      for (int u = 0; u < 8; ++u){
        if (u < rem){
          int p = pu8[u];
          float eev = Bs[((p >> 16) & 7)*64 + j]
                    + Bs[(8 + ((p >> 19) & 7))*64 + j]
                    + Bs[(16 + ((p >> 22) & 7))*64 + j];
          float mm = fmaxf(hv8[u] + eev, 0.f) + MSG_EPS;
          float ex = __expf(mm);
          den[r] += ex;
          num[r] = fmaf(ex, mm, num[r]);
        }
      }
    }
  }

  // finalize + T write
  #pragma unroll
  for (int r = 0; r < 4; ++r){
    float tv = own[r];
    if (e1a[r] > e0a[r]) tv = own[r] + num[r] / fmaxf(den[r], 1e-16f);
    T[w*4 + r][j] = f2bu(tv);
  }
  __syncthreads();                    // T now complete; waves cross-read

  // ---- GEMM: wave w -> 16x16 tile, cols w*16..w*16+15, rows v0..v0+15
  int ct = w;
  int quad = j >> 4, lm = j & 15;
  const uint4* Wfv = (const uint4*)Wf;
  uint4 B0 = Wfv[(size_t)(0*4 + ct)*64 + j];
  uint4 B1 = Wfv[(size_t)(1*4 + ct)*64 + j];
  uint4 A0 = *(const uint4*)&T[lm][8*quad];
  uint4 A1 = *(const uint4*)&T[lm][32 + 8*quad];
  f4v acc = (f4v){0.f,0.f,0.f,0.f};
  acc = mfma16(A0, B0, acc);
  acc = mfma16(A1, B1, acc);

  int col = ct*16 + lm;
  float bv = bias[col];
  float s1[4], s2[4];
  #pragma unroll
  for (int reg = 0; reg < 4; ++reg){
    int row = v0 + quad*4 + reg;
    float val = acc[reg] + bv;
    if (use_res && row < n) val += bu2f(hres[((unsigned)row << 6) + col]);
    acc[reg] = val;
    s1[reg] = val;
    s2[reg] = val*val;
  }
  // reduce over the 16 lanes of this quad-group (cols of the tile)
  #pragma unroll
  for (int reg = 0; reg < 4; ++reg){
    #pragma unroll
    for (int m = 1; m < 16; m <<= 1){
      s1[reg] += __shfl_xor(s1[reg], m, 64);
      s2[reg] += __shfl_xor(s2[reg], m, 64);
    }
  }
  if (lm == 0){
    #pragma unroll
    for (int reg = 0; reg < 4; ++reg){
      int rl = quad*4 + reg;
      PS1[ct][rl] = s1[reg];
      PS2[ct][rl] = s2[reg];
    }
  }
  __syncthreads();

  if (mode == 0){
    // hres + rowstat + in-register h2 -> LDS (stride 65) -> vt atomics
    float* H2 = Bs;                   // Bs free after agg phase; 16*65=1040<=1536
    #pragma unroll
    for (int reg = 0; reg < 4; ++reg){
      int rl = quad*4 + reg;
      int row = v0 + rl;
      if (row >= n) continue;
      hres[((size_t)row << 6) + col] = f2bu(acc[reg]);
      float t1 = PS1[0][rl] + PS1[1][rl] + PS1[2][rl] + PS1[3][rl];
      float t2 = PS2[0][rl] + PS2[1][rl] + PS2[2][rl] + PS2[3][rl];
      float mu = t1 * (1.f/64.f);
      float var = fmaxf(t2 * (1.f/64.f) - mu*mu, 0.f);
      float rstd = rsqrtf(var + LN_EPS);
      if (ct == 0 && lm == 0) rowstat[row] = make_float2(mu, rstd);
      H2[rl*65 + col] = fmaxf((acc[reg] - mu) * rstd * ng[col] + nb[col], 0.f);
    }
    __syncthreads();
    // thread (w, j): rows w*4..w*4+3, column j; segment by graph id
    float a = 0.f; int gc = -1;
    #pragma unroll
    for (int r = 0; r < 4; ++r){
      int rl = w*4 + r;
      int g = batch_lds[rl];          // -1 for rows >= n
      if (g >= 0){
        if (g != gc){
          if (gc >= 0) atomicAdd(&vt[(unsigned)gc*64 + j], a);
          gc = g; a = 0.f;
        }
        a += H2[rl*65 + j];
      }
    }
    if (gc >= 0) atomicAdd(&vt[(unsigned)gc*64 + j], a);
    return;
  }

  bool isf = (*flag != 0);
  #pragma unroll
  for (int reg = 0; reg < 4; ++reg){
    int rl = quad*4 + reg;
    int row = v0 + rl;
    if (row >= n) continue;
    float t1 = PS1[0][rl] + PS1[1][rl] + PS1[2][rl] + PS1[3][rl];
    float t2 = PS2[0][rl] + PS2[1][rl] + PS2[2][rl] + PS2[3][rl];
    float mu = t1 * (1.f/64.f);
    float var = fmaxf(t2 * (1.f/64.f) - mu*mu, 0.f);
    float rstd = rsqrtf(var + LN_EPS);
    float y = (acc[reg] - mu) * rstd * ng[col] + nb[col];
    size_t o = ((size_t)row << 6) + col;
    if (isf) ((float*)finalout)[o] = y;
    else     ((bf16*)finalout)[o]  = __float2bfloat16(y);
  }
}

// Virtualnode update + addvn. Segsum arrives precomputed in vt (built by
// k_layer's epilogue). Block g: s = vt[g]+vn_prev (re-zero vt[g] for next
// layer), 2x MLP/LN (64 threads), then per-lane addvn pass (hres + rowstat
// rebuild of h2; no cross-lane work -- R7 lesson).
__global__ __launch_bounds__(512) void k_vn(
    const unsigned short* __restrict__ hres, const float2* __restrict__ rowstat,
    float* __restrict__ vt, const int* __restrict__ goffs,
    const float* __restrict__ vn_emb, float* __restrict__ vn,
    unsigned short* __restrict__ b0,
    const float* __restrict__ ng, const float* __restrict__ nbb,
    const float* __restrict__ W1, const float* __restrict__ b1,
    const float* __restrict__ g1, const float* __restrict__ be1,
    const float* __restrict__ W2, const float* __restrict__ b2,
    const float* __restrict__ g2, const float* __restrict__ be2,
    int first){
  __shared__ float Ws[4096];
  __shared__ float rowbuf[64];
  __shared__ float vnew[64];
  int tid = threadIdx.x, w = tid >> 6, j = tid & 63, g = blockIdx.x;
  float ngj = ng[j], nbj = nbb[j];
  for (int idx = tid; idx < 4096; idx += 512) Ws[idx] = W1[idx];
  int r0 = goffs[g], r1 = goffs[g+1];
  if (tid < 64){
    float s = vt[(unsigned)g*64 + j]
            + (first ? vn_emb[j] : vn[(unsigned)g*64 + j]);
    vt[(unsigned)g*64 + j] = 0.f;     // re-arm for next layer's k_layer
    rowbuf[j] = s;
  }
  __syncthreads();
  float y = 0.f;
  if (tid < 64){
    float acc = b1[j];
    #pragma unroll
    for (int k = 0; k < 64; ++k) acc = fmaf(rowbuf[k], Ws[k*64 + j], acc);
    float mu = wave_sum64(acc) * (1.f/64.f);
    float d = acc - mu;
    float var = wave_sum64(d*d) * (1.f/64.f);
    y = fmaxf(d * rsqrtf(var + LN_EPS) * g1[j] + be1[j], 0.f);
  }
  __syncthreads();
  for (int idx = tid; idx < 4096; idx += 512) Ws[idx] = W2[idx];
  if (tid < 64) rowbuf[j] = y;
  __syncthreads();
  if (tid < 64){
    float acc = b2[j];
    #pragma unroll
    for (int k = 0; k < 64; ++k) acc = fmaf(rowbuf[k], Ws[k*64 + j], acc);
    float mu = wave_sum64(acc) * (1.f/64.f);
    float d = acc - mu;
    float var = wave_sum64(d*d) * (1.f/64.f);
    float v2 = fmaxf(d * rsqrtf(var + LN_EPS) * g2[j] + be2[j], 0.f);
    vn[(unsigned)g*64 + j] = v2;
    vnew[j] = v2;
  }
  __syncthreads();
  float vj = vnew[j];
  for (int i = r0 + w; i < r1; i += 8){
    float xv = bu2f(hres[((unsigned)i << 6) + j]);
    float2 st = rowstat[i];
    float h2 = fmaxf((xv - st.x) * st.y * ngj + nbj, 0.f);
    b0[((unsigned)i << 6) + j] = f2bu(h2 + vj);
  }
}

extern "C" void kernel_launch(void* const* d_in, const int* in_sizes, int n_in,
                              void* d_out, int out_size, void* d_ws, size_t ws_size,
                              hipStream_t stream){
  const int* x          = (const int*)d_in[0];
  const int* edge_index = (const int*)d_in[1];
  const int* edge_attr  = (const int*)d_in[2];
  const int* batch      = (const int*)d_in[3];

  const int N = in_sizes[3];
  const int E = in_sizes[2] / 3;
  const int L = 4;

  const int P_ATOM = 0, P_BOND = 36864, P_GW = 38400, P_GB = 54784,
            P_NG = 55040, P_NB = 55296, P_VNE = 55552, P_W1 = 55616,
            P_B1 = 67904, P_G1 = 68096, P_BE1 = 68288, P_W2 = 68480,
            P_B2 = 80768, P_G2 = 80960, P_BE2 = 81152, P_END = 81344;

  char* ws = (char*)d_ws;
  size_t off = 0;
  auto alloc = [&](size_t bytes)->char*{
    char* p = ws + off; off += (bytes + 255) & ~(size_t)255; return p;
  };
  int*    flag   = (int*)alloc(256);
  float*  par    = (float*)alloc((size_t)P_END * 4);
  unsigned short* Wf  = (unsigned short*)alloc(16384 * 2);
  unsigned short* b0  = (unsigned short*)alloc((size_t)N*64*2);
  unsigned short* hres= (unsigned short*)alloc((size_t)N*64*2);
  float2* rowstat= (float2*)alloc((size_t)N*8);
  float*  vt     = (float*)alloc((size_t)GNUM*64*4);
  int*    counts = (int*)alloc((size_t)N*4);
  int*    offs   = (int*)alloc((size_t)(N+1)*4);
  int*    cursor = (int*)alloc((size_t)N*4);
  int*    btot   = (int*)alloc(1024);
  int*    bexc   = (int*)alloc(1024);
  int*    payload= (int*)alloc((size_t)E*4);
  int*    goffs  = (int*)alloc((size_t)(GNUM+1)*4);
  float*  vn     = (float*)alloc((size_t)GNUM*64*4);
  (void)ws_size; (void)n_in; (void)out_size;

  Params15 P;
  const int poffs[15] = {P_ATOM,P_BOND,P_GW,P_GB,P_NG,P_NB,P_VNE,P_W1,P_B1,P_G1,P_BE1,P_W2,P_B2,P_G2,P_BE2};
  for (int a = 0; a < 15; ++a){ P.src[a] = d_in[4+a]; P.n[a] = in_sizes[4+a]; P.off[a] = poffs[a]; }

  int nodeGrid = (N*64 + 255) / 256;
  int nScanB   = (N + 255) / 256;
  int eGrid    = (E + 255) / 256;
  const int* srcp = edge_index;
  const int* dstp = edge_index + E;

  // counts must be zero BEFORE k_front (count role atomics) -- memset node
  hipMemsetAsync(counts, 0, (size_t)N*4, stream);
  k_front<<<194 + eGrid + nodeGrid, 256, 0, stream>>>(P, flag, par, counts,
                                                      vt, GNUM*64, x, batch,
                                                      dstp, Wf, goffs, b0,
                                                      N, E, eGrid);
  k_scan1<<<nScanB, 256, 0, stream>>>(counts, offs, cursor, btot, N);
  k_scan2<<<1, 256, 0, stream>>>(btot, bexc, nScanB);
  k_scatfin<<<nScanB + eGrid, 256, 0, stream>>>(srcp, dstp, edge_attr, offs,
                                                cursor, bexc, payload, N, E, nScanB);

  int layerGrid = (N + 15) / 16;
  for (int l = 0; l < L; ++l){
    if (l > 0){
      k_vn<<<GNUM, 512, 0, stream>>>(hres, rowstat, vt, goffs, par + P_VNE, vn, b0,
                                     par + P_NG + (l-1)*64, par + P_NB + (l-1)*64,
                                     par + P_W1 + (l-1)*4096, par + P_B1 + (l-1)*64,
                                     par + P_G1 + (l-1)*64, par + P_BE1 + (l-1)*64,
                                     par + P_W2 + (l-1)*4096, par + P_B2 + (l-1)*64,
                                     par + P_G2 + (l-1)*64, par + P_BE2 + (l-1)*64,
                                     l == 1 ? 1 : 0);
    }
    int mode = (l == L-1) ? 1 : 0;
    k_layer<<<layerGrid, 256, 0, stream>>>(b0, offs, payload, par + P_BOND,
                                           Wf + (size_t)l*4096, par + P_GB + l*64,
                                           batch, vt, hres, rowstat, d_out,
                                           par + P_NG + l*64, par + P_NB + l*64,
                                           flag, l > 0 ? 1 : 0, mode, N);
  }
}

// Round 14
// 332.077 us; speedup vs baseline: 1.2281x; 1.2281x over previous
//
#include <hip/hip_runtime.h>
#include <hip/hip_bf16.h>

typedef __hip_bfloat16 bf16;

#define GNUM 256
#define LN_EPS 1e-5f
#define MSG_EPS 1e-7f

typedef float f4v __attribute__((ext_vector_type(4)));
typedef short s8v __attribute__((ext_vector_type(8)));
typedef __bf16 b8v __attribute__((ext_vector_type(8)));

template <typename V>
__device__ auto mfma_bf16_(V a, V b, f4v c, int)
    -> decltype(__builtin_amdgcn_mfma_f32_16x16x32_bf16(a, b, c, 0, 0, 0)) {
  return __builtin_amdgcn_mfma_f32_16x16x32_bf16(a, b, c, 0, 0, 0);
}
template <typename V>
__device__ f4v mfma_bf16_(V a, V b, f4v c, long) {
  return __builtin_amdgcn_mfma_f32_16x16x32_bf16(__builtin_bit_cast(s8v, a),
                                                 __builtin_bit_cast(s8v, b), c, 0, 0, 0);
}
__device__ __forceinline__ f4v mfma16(uint4 a, uint4 b, f4v c){
  return mfma_bf16_(__builtin_bit_cast(b8v, a), __builtin_bit_cast(b8v, b), c, 0);
}

__device__ __forceinline__ float bu2f(unsigned short u){
  unsigned v = ((unsigned)u) << 16; return __builtin_bit_cast(float, v);
}
__device__ __forceinline__ unsigned short f2bu(float f){
  unsigned u = __builtin_bit_cast(unsigned, f);
  return (unsigned short)((u + 0x7FFFu + ((u >> 16) & 1u)) >> 16);
}

__device__ __forceinline__ float wave_sum64(float v){
  #pragma unroll
  for (int off = 32; off > 0; off >>= 1) v += __shfl_xor(v, off, 64);
  return v;
}

struct Params15 {
  const void* src[15];
  int n[15];
  int off[15];
};

// JOURNAL:
//  R5: no cooperative grid.sync -- ~100us/sync on 8 XCDs.
//  R7: no serial wave_sum64 recompute in low-occupancy k_vn (+58us).
//  R8: mode-0 k_layer write-bytes NOT on critical path (gather-bound).
//  R9: always-16 agg batch regressed (+38% gather issues); vt-fold WORKED.
//  R10: deg-specialized batch (8/16 by deg) + vt-fold = 337us best.
//  R11: k_prep merged into k_front = 332us.
//  R12: CSR chain 5->3 dispatches: neutral -- prologue launches ~free.
//  R13: 4-row-interleaved batch REGRESSED (VGPR 28->52, occ 53->34%, +14us/
//       k_layer): agg is at a TLP-vs-ILP equilibrium -- buying ILP with
//       registers loses more TLP than it gains. REVERTED to R12/R10 agg.

// k_front block roles (each derives isf locally; roles read RAW inputs):
//   0..127          : param convert -> par, zero vt, block0 publishes flag
//   128..191        : permute gcn_W (raw src[2]) into MFMA B-frag order Wf
//   192..193        : goffs binary search over batch
//   194..194+eGrid  : degree count atomics (counts pre-zeroed by memset)
//   rest            : node encode b0[i,:] = bf16(sum_f atom_emb + vn_emb)
__global__ __launch_bounds__(256) void k_front(
    Params15 P, int* __restrict__ flag, float* __restrict__ par,
    int* __restrict__ counts, float* __restrict__ vt, int nvt,
    const int* __restrict__ x, const int* __restrict__ batch,
    const int* __restrict__ dstp,
    unsigned short* __restrict__ Wf, int* __restrict__ goffs,
    unsigned short* __restrict__ b0, int n, int E, int eGrid){
  __shared__ int isf_sh;
  int tid = threadIdx.x, bid = blockIdx.x;
  if (tid < 64){
    const unsigned short* u = (const unsigned short*)P.src[0];
    int bad = 0;
    for (int k = tid; k < 256; k += 64){
      unsigned short v = u[2*k];
      if (((v >> 7) & 0xFFu) >= 137u) bad = 1;
    }
    unsigned long long m = __ballot(bad);
    if (tid == 0) isf_sh = (m != 0ull) ? 1 : 0;
  }
  __syncthreads();
  bool isf = (isf_sh != 0);

  if (bid < 128){
    if (bid == 0 && tid == 0) *flag = isf ? 1 : 0;
    int stride = 128*256;
    int gid = bid*256 + tid;
    for (int a = 0; a < 15; ++a){
      int nn = P.n[a];
      float* d = par + P.off[a];
      if (isf){
        const float* s = (const float*)P.src[a];
        for (int i = gid; i < nn; i += stride) d[i] = s[i];
      } else {
        const bf16* s = (const bf16*)P.src[a];
        for (int i = gid; i < nn; i += stride) d[i] = __bfloat162float(s[i]);
      }
    }
    for (int i = gid; i < nvt; i += stride) vt[i] = 0.f;
  } else if (bid < 192){
    int t = (bid - 128)*256 + tid;      // 16384 total
    int j = t & 7, lane = (t >> 3) & 63, nt = (t >> 9) & 3, kt = (t >> 11) & 1, l = t >> 12;
    int k = kt*32 + (lane >> 4)*8 + j;
    int c = nt*16 + (lane & 15);
    int src = l*4096 + k*64 + c;
    if (isf) Wf[t] = f2bu(((const float*)P.src[2])[src]);
    else     Wf[t] = ((const unsigned short*)P.src[2])[src];
  } else if (bid < 194){
    int g = (bid - 192)*256 + tid;
    if (g > GNUM) return;
    if (g == GNUM){ goffs[GNUM] = n; return; }
    int lo = 0, hi = n;
    while (lo < hi){ int mid = (lo+hi)>>1; if (batch[mid] < g) lo = mid+1; else hi = mid; }
    goffs[g] = lo;
  } else if (bid < 194 + eGrid){
    int e = (bid - 194)*256 + tid;
    if (e < E) atomicAdd(counts + dstp[e], 1);
  } else {
    int t = (bid - 194 - eGrid) * 256 + tid;
    int i = t >> 6, j = t & 63;
    if (i >= n) return;
    float acc;
    if (isf){
      const float* ae = (const float*)P.src[0];
      acc = ((const float*)P.src[6])[j];
      #pragma unroll
      for (int f = 0; f < 9; ++f){
        int idx = x[i*9 + f];
        acc += ae[(f*64 + idx)*64 + j];
      }
    } else {
      const unsigned short* ae = (const unsigned short*)P.src[0];
      acc = bu2f(((const unsigned short*)P.src[6])[j]);
      #pragma unroll
      for (int f = 0; f < 9; ++f){
        int idx = x[i*9 + f];
        acc += bu2f(ae[(f*64 + idx)*64 + j]);
      }
    }
    b0[t] = f2bu(acc);
  }
}

// scan1: per-chunk inclusive scan -> offs[i+1] (partial), plus
// cursor[i] = partial EXCLUSIVE prefix (lets scatter add bexc on the fly).
__global__ __launch_bounds__(256) void k_scan1(const int* __restrict__ counts,
                                               int* __restrict__ offs,
                                               int* __restrict__ cursor,
                                               int* __restrict__ btot, int n){
  __shared__ int wsum[4];
  int tid = threadIdx.x, w = tid >> 6, lane = tid & 63;
  int i = blockIdx.x*256 + tid;
  int v = (i < n) ? counts[i] : 0;
  int incl = v;
  #pragma unroll
  for (int off = 1; off < 64; off <<= 1){
    int t = __shfl_up(incl, off, 64);
    if (lane >= off) incl += t;
  }
  if (lane == 63) wsum[w] = incl;
  __syncthreads();
  int woff = 0;
  for (int k = 0; k < w; ++k) woff += wsum[k];
  int tot = incl + woff;
  if (i < n){
    offs[i+1] = tot;
    cursor[i] = tot - v;              // partial exclusive
  }
  if (tid == 255) btot[blockIdx.x] = tot;
}

__global__ __launch_bounds__(256) void k_scan2(const int* __restrict__ btot,
                                               int* __restrict__ bexc, int nb){
  __shared__ int wsum[4];
  __shared__ int carry_sh;
  int tid = threadIdx.x, w = tid >> 6, lane = tid & 63;
  if (tid == 0) carry_sh = 0;
  __syncthreads();
  for (int base = 0; base < nb; base += 256){
    int i = base + tid;
    int v = (i < nb) ? btot[i] : 0;
    int incl = v;
    #pragma unroll
    for (int off = 1; off < 64; off <<= 1){
      int t = __shfl_up(incl, off, 64);
      if (lane >= off) incl += t;
    }
    if (lane == 63) wsum[w] = incl;
    __syncthreads();
    int carry = carry_sh;
    int woff = 0;
    for (int k = 0; k < w; ++k) woff += wsum[k];
    if (i < nb) bexc[i] = carry + woff + incl - v;
    __syncthreads();
    if (tid == 0) carry_sh = carry + wsum[0] + wsum[1] + wsum[2] + wsum[3];
    __syncthreads();
  }
}

// k_scatfin = merged scan3 + scatter (role-split, no intra-kernel dependency)
__global__ void k_scatfin(const int* __restrict__ src, const int* __restrict__ dst,
                          const int* __restrict__ ea, int* __restrict__ offs,
                          int* __restrict__ cursor, const int* __restrict__ bexc,
                          int* __restrict__ payload, int n, int E, int nScanB){
  int bid = blockIdx.x, tid = threadIdx.x;
  if (bid < nScanB){
    int i = bid*256 + tid;
    if (i == 0) offs[0] = 0;
    if (i < n) offs[i+1] += bexc[bid];
  } else {
    int e = (bid - nScanB)*256 + tid;
    if (e >= E) return;
    int d = dst[e];
    int pos = atomicAdd(cursor + d, 1) + bexc[d >> 8];
    payload[pos] = (src[e] & 0xFFFF) | (ea[e*3] << 16) | (ea[e*3+1] << 19) | (ea[e*3+2] << 22);
  }
}

// Fused GENConv layer, 256 threads = 4 waves, block owns 16 rows.
// Agg: DEG-SPECIALIZED single batch (wave-uniform branch on rem):
//   deg<=8 -> one 8-batch; deg<=16 -> one 16-batch; deg>16 -> +8-loop.
// All loads unguarded clamped (pipelined); compute uniform-skipped.
// Epilogue (mode 0): hres+rowstat + h2 into H2 LDS (stride 65) -> vt atomics.
// mode 1: finalout = LN(.)
__global__ __launch_bounds__(256) void k_layer(
    const unsigned short* __restrict__ b0, const int* __restrict__ offs,
    const int* __restrict__ payload, const float* __restrict__ bond,
    const unsigned short* __restrict__ Wf, const float* __restrict__ bias,
    const int* __restrict__ batch, float* __restrict__ vt,
    unsigned short* __restrict__ hres, float2* __restrict__ rowstat,
    void* __restrict__ finalout, const float* __restrict__ ng,
    const float* __restrict__ nb, const int* __restrict__ flag,
    int use_res, int mode, int n){
  __shared__ float Bs[1536];          // bond tables during agg; H2 staging in epilogue
  __shared__ __align__(16) unsigned short T[16][72];  // 144B row stride: 2-way alias = free
  __shared__ float PS1[4][16], PS2[4][16];
  __shared__ int batch_lds[16];
  int tid = threadIdx.x;
  int v0 = blockIdx.x * 16;
  for (int idx = tid; idx < 1536; idx += 256) Bs[idx] = bond[idx];
  if (tid < 16){ int rw = v0 + tid; batch_lds[tid] = (rw < n) ? batch[rw] : -1; }
  __syncthreads();
  int w = tid >> 6, j = tid & 63;
  int vb = v0 + w*4;                  // this wave's 4 rows

  // hoist the 5 CSR offsets for this wave: one coalesced lane-parallel load
  int oidx = vb + (j < 5 ? j : 4);
  if (oidx > n) oidx = n;
  int o5 = offs[oidx];

  for (int r = 0; r < 4; ++r){
    int v = vb + r;
    float tv = 0.f;
    if (v < n){
      // wave-uniform edge range in SGPRs -> payload loads become scalar loads
      int e0 = __builtin_amdgcn_readfirstlane(__shfl(o5, r, 64));
      int e1 = __builtin_amdgcn_readfirstlane(__shfl(o5, r + 1, 64));
      float own = bu2f(b0[((unsigned)v << 6) + j]);
      tv = own;
      if (e1 > e0){
        float den = 0.f, num = 0.f;
        int rem0 = e1 - e0;                    // uniform, >= 1
        if (rem0 <= 8){
          // single 8-batch (59% of rows)
          int pu[8]; float hv[8];
          #pragma unroll
          for (int u = 0; u < 8; ++u){
            int ei = (u < rem0) ? e0 + u : e0;
            pu[u] = payload[ei];
          }
          #pragma unroll
          for (int u = 0; u < 8; ++u)
            hv[u] = bu2f(b0[((unsigned)(pu[u] & 0xFFFF) << 6) + j]);
          if (rem0 >= 8){
            #pragma unroll
            for (int u = 0; u < 8; ++u){
              int p = pu[u];
              float eev = Bs[((p >> 16) & 7)*64 + j]
                        + Bs[(8 + ((p >> 19) & 7))*64 + j]
                        + Bs[(16 + ((p >> 22) & 7))*64 + j];
              float mm = fmaxf(hv[u] + eev, 0.f) + MSG_EPS;
              float ex = __expf(mm);
              den += ex;
              num = fmaf(ex, mm, num);
            }
          } else {
            #pragma unroll
            for (int u = 0; u < 8; ++u){
              if (u < rem0){
                int p = pu[u];
                float eev = Bs[((p >> 16) & 7)*64 + j]
                          + Bs[(8 + ((p >> 19) & 7))*64 + j]
                          + Bs[(16 + ((p >> 22) & 7))*64 + j];
                float mm = fmaxf(hv[u] + eev, 0.f) + MSG_EPS;
                float ex = __expf(mm);
                den += ex;
                num = fmaf(ex, mm, num);
              }
            }
          }
        } else {
          // single 16-batch (40%: deg 9..16 single chain; deg>16 falls through)
          int pu[16]; float hv[16];
          #pragma unroll
          for (int u = 0; u < 16; ++u){
            int ei = (u < rem0) ? e0 + u : e0;
            pu[u] = payload[ei];
          }
          #pragma unroll
          for (int u = 0; u < 16; ++u)
            hv[u] = bu2f(b0[((unsigned)(pu[u] & 0xFFFF) << 6) + j]);
          if (rem0 >= 16){
            #pragma unroll
            for (int u = 0; u < 16; ++u){
              int p = pu[u];
              float eev = Bs[((p >> 16) & 7)*64 + j]
                        + Bs[(8 + ((p >> 19) & 7))*64 + j]
                        + Bs[(16 + ((p >> 22) & 7))*64 + j];
              float mm = fmaxf(hv[u] + eev, 0.f) + MSG_EPS;
              float ex = __expf(mm);
              den += ex;
              num = fmaf(ex, mm, num);
            }
          } else {
            #pragma unroll
            for (int u = 0; u < 16; ++u){
              if (u < rem0){
                int p = pu[u];
                float eev = Bs[((p >> 16) & 7)*64 + j]
                          + Bs[(8 + ((p >> 19) & 7))*64 + j]
                          + Bs[(16 + ((p >> 22) & 7))*64 + j];
                float mm = fmaxf(hv[u] + eev, 0.f) + MSG_EPS;
                float ex = __expf(mm);
                den += ex;
                num = fmaf(ex, mm, num);
              }
            }
          }
          // rare fallback: deg > 16 (P ~ 1e-3)
          for (int e = e0 + 16; e < e1; e += 8){
            int rem = e1 - e;
            int pu8[8]; float hv8[8];
            #pragma unroll
            for (int u = 0; u < 8; ++u){
              int ei = (u < rem) ? e + u : e0;
              pu8[u] = payload[ei];
            }
            #pragma unroll
            for (int u = 0; u < 8; ++u)
              hv8[u] = bu2f(b0[((unsigned)(pu8[u] & 0xFFFF) << 6) + j]);
            #pragma unroll
            for (int u = 0; u < 8; ++u){
              if (u < rem){
                int p = pu8[u];
                float eev = Bs[((p >> 16) & 7)*64 + j]
                          + Bs[(8 + ((p >> 19) & 7))*64 + j]
                          + Bs[(16 + ((p >> 22) & 7))*64 + j];
                float mm = fmaxf(hv8[u] + eev, 0.f) + MSG_EPS;
                float ex = __expf(mm);
                den += ex;
                num = fmaf(ex, mm, num);
              }
            }
          }
        }
        tv = own + num / fmaxf(den, 1e-16f);
      }
    }
    T[w*4 + r][j] = f2bu(tv);
  }
  __syncthreads();                    // T now complete; waves cross-read

  // ---- GEMM: wave w -> 16x16 tile, cols w*16..w*16+15, rows v0..v0+15
  int ct = w;
  int quad = j >> 4, lm = j & 15;
  const uint4* Wfv = (const uint4*)Wf;
  uint4 B0 = Wfv[(size_t)(0*4 + ct)*64 + j];
  uint4 B1 = Wfv[(size_t)(1*4 + ct)*64 + j];
  uint4 A0 = *(const uint4*)&T[lm][8*quad];
  uint4 A1 = *(const uint4*)&T[lm][32 + 8*quad];
  f4v acc = (f4v){0.f,0.f,0.f,0.f};
  acc = mfma16(A0, B0, acc);
  acc = mfma16(A1, B1, acc);

  int col = ct*16 + lm;
  float bv = bias[col];
  float s1[4], s2[4];
  #pragma unroll
  for (int reg = 0; reg < 4; ++reg){
    int row = v0 + quad*4 + reg;
    float val = acc[reg] + bv;
    if (use_res && row < n) val += bu2f(hres[((unsigned)row << 6) + col]);
    acc[reg] = val;
    s1[reg] = val;
    s2[reg] = val*val;
  }
  // reduce over the 16 lanes of this quad-group (cols of the tile)
  #pragma unroll
  for (int reg = 0; reg < 4; ++reg){
    #pragma unroll
    for (int m = 1; m < 16; m <<= 1){
      s1[reg] += __shfl_xor(s1[reg], m, 64);
      s2[reg] += __shfl_xor(s2[reg], m, 64);
    }
  }
  if (lm == 0){
    #pragma unroll
    for (int reg = 0; reg < 4; ++reg){
      int rl = quad*4 + reg;
      PS1[ct][rl] = s1[reg];
      PS2[ct][rl] = s2[reg];
    }
  }
  __syncthreads();

  if (mode == 0){
    // hres + rowstat + in-register h2 -> LDS (stride 65) -> vt atomics
    float* H2 = Bs;                   // Bs free after agg phase; 16*65=1040<=1536
    #pragma unroll
    for (int reg = 0; reg < 4; ++reg){
      int rl = quad*4 + reg;
      int row = v0 + rl;
      if (row >= n) continue;
      hres[((size_t)row << 6) + col] = f2bu(acc[reg]);
      float t1 = PS1[0][rl] + PS1[1][rl] + PS1[2][rl] + PS1[3][rl];
      float t2 = PS2[0][rl] + PS2[1][rl] + PS2[2][rl] + PS2[3][rl];
      float mu = t1 * (1.f/64.f);
      float var = fmaxf(t2 * (1.f/64.f) - mu*mu, 0.f);
      float rstd = rsqrtf(var + LN_EPS);
      if (ct == 0 && lm == 0) rowstat[row] = make_float2(mu, rstd);
      H2[rl*65 + col] = fmaxf((acc[reg] - mu) * rstd * ng[col] + nb[col], 0.f);
    }
    __syncthreads();
    // thread (w, j): rows w*4..w*4+3, column j; segment by graph id
    float a = 0.f; int gc = -1;
    #pragma unroll
    for (int r = 0; r < 4; ++r){
      int rl = w*4 + r;
      int g = batch_lds[rl];          // -1 for rows >= n
      if (g >= 0){
        if (g != gc){
          if (gc >= 0) atomicAdd(&vt[(unsigned)gc*64 + j], a);
          gc = g; a = 0.f;
        }
        a += H2[rl*65 + j];
      }
    }
    if (gc >= 0) atomicAdd(&vt[(unsigned)gc*64 + j], a);
    return;
  }

  bool isf = (*flag != 0);
  #pragma unroll
  for (int reg = 0; reg < 4; ++reg){
    int rl = quad*4 + reg;
    int row = v0 + rl;
    if (row >= n) continue;
    float t1 = PS1[0][rl] + PS1[1][rl] + PS1[2][rl] + PS1[3][rl];
    float t2 = PS2[0][rl] + PS2[1][rl] + PS2[2][rl] + PS2[3][rl];
    float mu = t1 * (1.f/64.f);
    float var = fmaxf(t2 * (1.f/64.f) - mu*mu, 0.f);
    float rstd = rsqrtf(var + LN_EPS);
    float y = (acc[reg] - mu) * rstd * ng[col] + nb[col];
    size_t o = ((size_t)row << 6) + col;
    if (isf) ((float*)finalout)[o] = y;
    else     ((bf16*)finalout)[o]  = __float2bfloat16(y);
  }
}

// Virtualnode update + addvn. Segsum arrives precomputed in vt (built by
// k_layer's epilogue). Block g: s = vt[g]+vn_prev (re-zero vt[g] for next
// layer), 2x MLP/LN (64 threads), then per-lane addvn pass (hres + rowstat
// rebuild of h2; no cross-lane work -- R7 lesson).
__global__ __launch_bounds__(512) void k_vn(
    const unsigned short* __restrict__ hres, const float2* __restrict__ rowstat,
    float* __restrict__ vt, const int* __restrict__ goffs,
    const float* __restrict__ vn_emb, float* __restrict__ vn,
    unsigned short* __restrict__ b0,
    const float* __restrict__ ng, const float* __restrict__ nbb,
    const float* __restrict__ W1, const float* __restrict__ b1,
    const float* __restrict__ g1, const float* __restrict__ be1,
    const float* __restrict__ W2, const float* __restrict__ b2,
    const float* __restrict__ g2, const float* __restrict__ be2,
    int first){
  __shared__ float Ws[4096];
  __shared__ float rowbuf[64];
  __shared__ float vnew[64];
  int tid = threadIdx.x, w = tid >> 6, j = tid & 63, g = blockIdx.x;
  float ngj = ng[j], nbj = nbb[j];
  for (int idx = tid; idx < 4096; idx += 512) Ws[idx] = W1[idx];
  int r0 = goffs[g], r1 = goffs[g+1];
  if (tid < 64){
    float s = vt[(unsigned)g*64 + j]
            + (first ? vn_emb[j] : vn[(unsigned)g*64 + j]);
    vt[(unsigned)g*64 + j] = 0.f;     // re-arm for next layer's k_layer
    rowbuf[j] = s;
  }
  __syncthreads();
  float y = 0.f;
  if (tid < 64){
    float acc = b1[j];
    #pragma unroll
    for (int k = 0; k < 64; ++k) acc = fmaf(rowbuf[k], Ws[k*64 + j], acc);
    float mu = wave_sum64(acc) * (1.f/64.f);
    float d = acc - mu;
    float var = wave_sum64(d*d) * (1.f/64.f);
    y = fmaxf(d * rsqrtf(var + LN_EPS) * g1[j] + be1[j], 0.f);
  }
  __syncthreads();
  for (int idx = tid; idx < 4096; idx += 512) Ws[idx] = W2[idx];
  if (tid < 64) rowbuf[j] = y;
  __syncthreads();
  if (tid < 64){
    float acc = b2[j];
    #pragma unroll
    for (int k = 0; k < 64; ++k) acc = fmaf(rowbuf[k], Ws[k*64 + j], acc);
    float mu = wave_sum64(acc) * (1.f/64.f);
    float d = acc - mu;
    float var = wave_sum64(d*d) * (1.f/64.f);
    float v2 = fmaxf(d * rsqrtf(var + LN_EPS) * g2[j] + be2[j], 0.f);
    vn[(unsigned)g*64 + j] = v2;
    vnew[j] = v2;
  }
  __syncthreads();
  float vj = vnew[j];
  for (int i = r0 + w; i < r1; i += 8){
    float xv = bu2f(hres[((unsigned)i << 6) + j]);
    float2 st = rowstat[i];
    float h2 = fmaxf((xv - st.x) * st.y * ngj + nbj, 0.f);
    b0[((unsigned)i << 6) + j] = f2bu(h2 + vj);
  }
}

extern "C" void kernel_launch(void* const* d_in, const int* in_sizes, int n_in,
                              void* d_out, int out_size, void* d_ws, size_t ws_size,
                              hipStream_t stream){
  const int* x          = (const int*)d_in[0];
  const int* edge_index = (const int*)d_in[1];
  const int* edge_attr  = (const int*)d_in[2];
  const int* batch      = (const int*)d_in[3];

  const int N = in_sizes[3];
  const int E = in_sizes[2] / 3;
  const int L = 4;

  const int P_ATOM = 0, P_BOND = 36864, P_GW = 38400, P_GB = 54784,
            P_NG = 55040, P_NB = 55296, P_VNE = 55552, P_W1 = 55616,
            P_B1 = 67904, P_G1 = 68096, P_BE1 = 68288, P_W2 = 68480,
            P_B2 = 80768, P_G2 = 80960, P_BE2 = 81152, P_END = 81344;

  char* ws = (char*)d_ws;
  size_t off = 0;
  auto alloc = [&](size_t bytes)->char*{
    char* p = ws + off; off += (bytes + 255) & ~(size_t)255; return p;
  };
  int*    flag   = (int*)alloc(256);
  float*  par    = (float*)alloc((size_t)P_END * 4);
  unsigned short* Wf  = (unsigned short*)alloc(16384 * 2);
  unsigned short* b0  = (unsigned short*)alloc((size_t)N*64*2);
  unsigned short* hres= (unsigned short*)alloc((size_t)N*64*2);
  float2* rowstat= (float2*)alloc((size_t)N*8);
  float*  vt     = (float*)alloc((size_t)GNUM*64*4);
  int*    counts = (int*)alloc((size_t)N*4);
  int*    offs   = (int*)alloc((size_t)(N+1)*4);
  int*    cursor = (int*)alloc((size_t)N*4);
  int*    btot   = (int*)alloc(1024);
  int*    bexc   = (int*)alloc(1024);
  int*    payload= (int*)alloc((size_t)E*4);
  int*    goffs  = (int*)alloc((size_t)(GNUM+1)*4);
  float*  vn     = (float*)alloc((size_t)GNUM*64*4);
  (void)ws_size; (void)n_in; (void)out_size;

  Params15 P;
  const int poffs[15] = {P_ATOM,P_BOND,P_GW,P_GB,P_NG,P_NB,P_VNE,P_W1,P_B1,P_G1,P_BE1,P_W2,P_B2,P_G2,P_BE2};
  for (int a = 0; a < 15; ++a){ P.src[a] = d_in[4+a]; P.n[a] = in_sizes[4+a]; P.off[a] = poffs[a]; }

  int nodeGrid = (N*64 + 255) / 256;
  int nScanB   = (N + 255) / 256;
  int eGrid    = (E + 255) / 256;
  const int* srcp = edge_index;
  const int* dstp = edge_index + E;

  // counts must be zero BEFORE k_front (count role atomics) -- memset node
  hipMemsetAsync(counts, 0, (size_t)N*4, stream);
  k_front<<<194 + eGrid + nodeGrid, 256, 0, stream>>>(P, flag, par, counts,
                                                      vt, GNUM*64, x, batch,
                                                      dstp, Wf, goffs, b0,
                                                      N, E, eGrid);
  k_scan1<<<nScanB, 256, 0, stream>>>(counts, offs, cursor, btot, N);
  k_scan2<<<1, 256, 0, stream>>>(btot, bexc, nScanB);
  k_scatfin<<<nScanB + eGrid, 256, 0, stream>>>(srcp, dstp, edge_attr, offs,
                                                cursor, bexc, payload, N, E, nScanB);

  int layerGrid = (N + 15) / 16;
  for (int l = 0; l < L; ++l){
    if (l > 0){
      k_vn<<<GNUM, 512, 0, stream>>>(hres, rowstat, vt, goffs, par + P_VNE, vn, b0,
                                     par + P_NG + (l-1)*64, par + P_NB + (l-1)*64,
                                     par + P_W1 + (l-1)*4096, par + P_B1 + (l-1)*64,
                                     par + P_G1 + (l-1)*64, par + P_BE1 + (l-1)*64,
                                     par + P_W2 + (l-1)*4096, par + P_B2 + (l-1)*64,
                                     par + P_G2 + (l-1)*64, par + P_BE2 + (l-1)*64,
                                     l == 1 ? 1 : 0);
    }
    int mode = (l == L-1) ? 1 : 0;
    k_layer<<<layerGrid, 256, 0, stream>>>(b0, offs, payload, par + P_BOND,
                                           Wf + (size_t)l*4096, par + P_GB + l*64,
                                           batch, vt, hres, rowstat, d_out,
                                           par + P_NG + l*64, par + P_NB + l*64,
                                           flag, l > 0 ? 1 : 0, mode, N);
  }
}